// Round 8
// baseline (187.254 us; speedup 1.0000x reference)
//
#include <hip/hip_runtime.h>
#include <hip/hip_bf16.h>

typedef unsigned short u16;
typedef _Float16 f16;
typedef __attribute__((ext_vector_type(8))) short s16x8;
typedef __attribute__((ext_vector_type(8))) _Float16 f16x8;
typedef __attribute__((ext_vector_type(4))) float f32x4;
typedef __attribute__((ext_vector_type(4))) unsigned short u16x4;

// ---------------- MFMA wrapper (f16) ----------------
template <typename T>
__device__ __forceinline__ auto mfma_try(T a, T b, f32x4 c, int)
    -> decltype(__builtin_amdgcn_mfma_f32_16x16x32_f16(a, b, c, 0, 0, 0)) {
  return __builtin_amdgcn_mfma_f32_16x16x32_f16(a, b, c, 0, 0, 0);
}
template <typename T>
__device__ __forceinline__ f32x4 mfma_try(T a, T b, f32x4 c, long) {
  return __builtin_amdgcn_mfma_f32_16x16x32_f16(
      __builtin_bit_cast(f16x8, a), __builtin_bit_cast(f16x8, b), c, 0, 0, 0);
}
__device__ __forceinline__ f32x4 MFMA16(s16x8 a, s16x8 b, f32x4 c) {
  return mfma_try(a, b, c, 0);
}

__device__ __forceinline__ void gload16(const void* g, void* s) {
  __builtin_amdgcn_global_load_lds(
      (const __attribute__((address_space(1))) void*)g,
      (__attribute__((address_space(3))) void*)s, 16, 0, 0);
}

__device__ __forceinline__ u16 f2h(float x) {
  f16 h = (f16)x;
  u16 u;
  __builtin_memcpy(&u, &h, 2);
  return u;
}
__device__ __forceinline__ float h2f(u16 u) {
  f16 h;
  __builtin_memcpy(&h, &u, 2);
  return (float)h;
}

#define LDS_SWZ(r, cb) ((cb) ^ (((r)&7) << 4))

// =============== 128x128x64 2-phase dbuf core (proven, ~835 TF) ============
struct Geom {
  int srow[4];    // tile row covered by issue i
  int scol[4];    // PRE-SWIZZLED f16 col (gload_lds source, rule 21)
  int scnat[4];   // natural element col (reg-staged loads)
  int wofs[4];    // swizzled LDS byte offset (reg-staged ds_write)
  int w, l, wr, wc;
};

__device__ __forceinline__ Geom make_geom() {
  Geom g;
  int tid = threadIdx.x;
  g.w = tid >> 6; g.l = tid & 63;
  g.wr = g.w >> 1; g.wc = g.w & 1;
#pragma unroll
  for (int i = 0; i < 4; ++i) {
    int off = i * 4096 + g.w * 1024 + g.l * 16;
    int r = off >> 7, cb = off & 127;
    g.srow[i] = r;
    g.scol[i] = LDS_SWZ(r, cb) >> 1;
    g.scnat[i] = cb >> 1;
    g.wofs[i] = r * 128 + LDS_SWZ(r, cb);
  }
  return g;
}

__device__ __forceinline__ void stage(const u16* pan, int ld, int k0,
                                      char* lds, const Geom& g) {
#pragma unroll
  for (int i = 0; i < 4; ++i)
    gload16(pan + (long)g.srow[i] * ld + k0 + g.scol[i],
            lds + i * 4096 + g.w * 1024);
}

__device__ __forceinline__ void compute_step(const char* lA, const char* lB,
                                             const Geom& g, f32x4 acc[4][4]) {
#pragma unroll
  for (int ks = 0; ks < 2; ++ks) {
    s16x8 af[4], bg[4];
#pragma unroll
    for (int m = 0; m < 4; ++m) {
      int r = g.wr * 64 + m * 16 + (g.l & 15);
      int cb = ks * 64 + ((g.l >> 4) << 4);
      af[m] = *(const s16x8*)(lA + r * 128 + LDS_SWZ(r, cb));
    }
#pragma unroll
    for (int n = 0; n < 4; ++n) {
      int r = g.wc * 64 + n * 16 + (g.l & 15);
      int cb = ks * 64 + ((g.l >> 4) << 4);
      bg[n] = *(const s16x8*)(lB + r * 128 + LDS_SWZ(r, cb));
    }
#pragma unroll
    for (int m = 0; m < 4; ++m)
#pragma unroll
      for (int n = 0; n < 4; ++n)
        acc[m][n] = MFMA16(af[m], bg[n], acc[m][n]);
  }
}

// both operands f16 via gload_lds (proj, qkt).
__device__ __forceinline__ void gemm_core(const u16* Apan, int lda,
                                          const u16* Bpan, int ldb, int nsteps,
                                          char* lA, char* lB, const Geom& g,
                                          f32x4 acc[4][4]) {
  stage(Apan, lda, 0, lA, g);
  stage(Bpan, ldb, 0, lB, g);
  __syncthreads();
  for (int t = 0; t < nsteps; ++t) {
    int cur = (t & 1) << 14;
    if (t + 1 < nsteps) {
      int nxt = ((t + 1) & 1) << 14;
      stage(Apan, lda, (t + 1) * 64, lA + nxt, g);
      stage(Bpan, ldb, (t + 1) * 64, lB + nxt, g);
    }
    compute_step(lA + cur, lB + cur, g, acc);
    if (t + 1 < nsteps) __syncthreads();
  }
}

// ---- fused-softmax A path (pv): A = exp(score - m) * inv, causal-masked ----
__device__ __forceinline__ void a_issue16(const u16* pan, int k0, const Geom& g,
                                          s16x8 (&ar)[4]) {
#pragma unroll
  for (int i = 0; i < 4; ++i)
    ar[i] = *(const s16x8*)(pan + (long)g.srow[i] * 2048 + k0 + g.scnat[i]);
}
__device__ __forceinline__ void a_write_exp(char* lA, const Geom& g,
                                            const s16x8 (&ar)[4], int k0,
                                            const float (&m4)[4],
                                            const float (&inv4)[4],
                                            const int (&iq4)[4]) {
#pragma unroll
  for (int i = 0; i < 4; ++i) {
    s16x8 h;
#pragma unroll
    for (int j = 0; j < 8; ++j) {
      int k = k0 + g.scnat[i] + j;
      float x = h2f((u16)ar[i][j]);
      float p = __expf(x - m4[i]) * inv4[i];
      p = (k <= iq4[i]) ? p : 0.0f;  // select AFTER exp: kills garbage/NaN
      h[j] = (short)f2h(p);
    }
    *(s16x8*)(lA + g.wofs[i]) = h;
  }
}

// A from raw scores (fused softmax-normalize), B f16 via gload_lds.
__device__ __forceinline__ void gemm_core_pexp(
    const u16* Ppan, const u16* Bpan, int ldb, int nsteps, char* lA, char* lB,
    const Geom& g, f32x4 acc[4][4], const float (&m4)[4],
    const float (&inv4)[4], const int (&iq4)[4]) {
  s16x8 ar[4];
  a_issue16(Ppan, 0, g, ar);
  stage(Bpan, ldb, 0, lB, g);
  a_write_exp(lA, g, ar, 0, m4, inv4, iq4);
  __syncthreads();
  for (int t = 0; t < nsteps; ++t) {
    int cur = (t & 1) << 14;
    int nxt = ((t + 1) & 1) << 14;
    if (t + 1 < nsteps) {
      a_issue16(Ppan, (t + 1) * 64, g, ar);          // loads in flight
      stage(Bpan, ldb, (t + 1) * 64, lB + nxt, g);
    }
    compute_step(lA + cur, lB + cur, g, acc);        // hides latency
    if (t + 1 < nsteps) {
      a_write_exp(lA + nxt, g, ar, (t + 1) * 64, m4, inv4, iq4);
      __syncthreads();
    }
  }
}

// ---------------- kernels ----------------
// merged projections: y=0 K, y=1 Q, y=2 V^T. M folded over batch (8192).
__global__ __launch_bounds__(256, 2) void proj_kernel(
    const u16* __restrict__ xk, const u16* __restrict__ xq, const u16* __restrict__ xv,
    const u16* __restrict__ wk, const u16* __restrict__ wq, const u16* __restrict__ wv,
    u16* __restrict__ K, u16* __restrict__ Q, u16* __restrict__ Vt) {
  __shared__ char lds[65536];
  const int y = blockIdx.y;
  const u16* X = y == 0 ? xk : (y == 1 ? xq : xv);
  const u16* W = y == 0 ? wk : (y == 1 ? wq : wv);
  const int bx = blockIdx.x;
  const int swz = (bx & 7) * 64 + (bx >> 3);  // 512 blocks, bijective
  const int tm = swz >> 3, tn = swz & 7;
  Geom g = make_geom();
  f32x4 acc[4][4] = {};
  gemm_core(X + (long)tm * 128 * 1024, 1024, W + (long)tn * 128 * 1024, 1024,
            16, lds, lds + 32768, g, acc);
  const int rg0 = tm * 128 + g.wr * 64, cg0 = tn * 128 + g.wc * 64;
  if (y < 2) {
    u16* C = y == 0 ? K : Q;
#pragma unroll
    for (int m = 0; m < 4; ++m)
#pragma unroll
      for (int n = 0; n < 4; ++n)
#pragma unroll
        for (int j = 0; j < 4; ++j) {
          int rg = rg0 + m * 16 + ((g.l >> 4) << 2) + j;
          int cg = cg0 + n * 16 + (g.l & 15);
          C[(long)rg * 1024 + cg] = f2h(acc[m][n][j]);
        }
  } else {
#pragma unroll
    for (int m = 0; m < 4; ++m) {
      int rg = rg0 + m * 16 + ((g.l >> 4) << 2);
      int b = rg >> 11, rl = rg & 2047;
#pragma unroll
      for (int n = 0; n < 4; ++n) {
        int cg = cg0 + n * 16 + (g.l & 15);
        u16x4 pk;
#pragma unroll
        for (int j = 0; j < 4; ++j) pk[j] = f2h(acc[m][n][j]);
        *(u16x4*)(Vt + (long)b * (1024 * 2048) + (long)cg * 2048 + rl) = pk;
      }
    }
  }
}

// scores = Q K^T, triangular tile grid, f16 out. 544 blocks (4 batches x 136).
__global__ __launch_bounds__(256, 2) void qkt_kernel(
    const u16* __restrict__ Q, const u16* __restrict__ K, u16* __restrict__ S) {
  __shared__ char lds[65536];
  const int bx = blockIdx.x;
  const int swz = (bx & 7) * 68 + (bx >> 3);  // 544 = 8*68, bijective
  const int b = swz / 136;
  int t = swz - b * 136;
  int tm = 0;
  while (t > tm) { t -= tm + 1; ++tm; }
  const int tn = t;
  Geom g = make_geom();
  f32x4 acc[4][4] = {};
  const u16* Qb = Q + (long)b * 2048 * 1024;
  const u16* Kb = K + (long)b * 2048 * 1024;
  gemm_core(Qb + (long)tm * 128 * 1024, 1024, Kb + (long)tn * 128 * 1024, 1024,
            16, lds, lds + 32768, g, acc);
  u16* Sb = S + (long)b * 2048 * 2048;
  const int rg0 = tm * 128 + g.wr * 64, cg0 = tn * 128 + g.wc * 64;
#pragma unroll
  for (int m = 0; m < 4; ++m)
#pragma unroll
    for (int n = 0; n < 4; ++n)
#pragma unroll
      for (int j = 0; j < 4; ++j) {
        int rg = rg0 + m * 16 + ((g.l >> 4) << 2) + j;
        int cg = cg0 + n * 16 + (g.l & 15);
        Sb[(long)rg * 2048 + cg] = f2h(acc[m][n][j]);
      }
}

// O = P V with P = exp(S - m)*inv computed on the fly from raw scores.
// k-limited per q-tile. 512 blocks.
__global__ __launch_bounds__(256, 2) void pv_kernel(
    const u16* __restrict__ S, const u16* __restrict__ Vt,
    const float* __restrict__ stats, float* __restrict__ O) {
  __shared__ char lds[65536];
  const int bx = blockIdx.x;
  const int swz = (bx & 7) * 64 + (bx >> 3);
  const int b = swz >> 7, loc = swz & 127;
  const int tm = loc >> 3, tn = loc & 7;
  Geom g = make_geom();
  float m4[4], inv4[4];
  int iq4[4];
#pragma unroll
  for (int i = 0; i < 4; ++i) {
    int row = tm * 128 + g.srow[i];            // i_q within batch
    iq4[i] = row;
    const float* st = stats + ((long)b * 2048 + row) * 2;
    m4[i] = st[0];
    inv4[i] = st[1];
  }
  f32x4 acc[4][4] = {};
  gemm_core_pexp(S + ((long)b * 2048 + tm * 128) * 2048,
                 Vt + (long)b * 1024 * 2048 + (long)tn * 128 * 2048, 2048,
                 (tm + 1) * 2, lds, lds + 32768, g, acc, m4, inv4, iq4);
  const int rg0 = tm * 128 + g.wr * 64, cg0 = tn * 128 + g.wc * 64;
#pragma unroll
  for (int m = 0; m < 4; ++m)
#pragma unroll
    for (int n = 0; n < 4; ++n)
#pragma unroll
      for (int j = 0; j < 4; ++j) {
        int rg = rg0 + m * 16 + ((g.l >> 4) << 2) + j;
        int cg = cg0 + n * 16 + (g.l & 15);
        O[((long)b * 2048 + rg) * 1024 + cg] = acc[m][n][j];
      }
}

// ---------------- row stats: per-row (max, 1/sum) of causal softmax --------
__global__ __launch_bounds__(256) void rowstat_kernel(
    const u16* __restrict__ S, float* __restrict__ stats) {
  const int row = blockIdx.x;  // b*2048 + i
  const int i_q = row & 2047;
  const u16* sr = S + (long)row * 2048;
  const int tid = threadIdx.x;
  const int l = tid & 63, w = tid >> 6;
  const int base = tid * 8;

  float v[8];
  float m = -INFINITY;
  if (base <= i_q) {  // read-skip fully-masked chunks
    s16x8 raw = *(const s16x8*)(sr + base);
#pragma unroll
    for (int j = 0; j < 8; ++j) {
      float x = h2f((u16)raw[j]);
      x = (base + j <= i_q) ? x : -INFINITY;
      v[j] = x;
      m = fmaxf(m, x);
    }
  } else {
#pragma unroll
    for (int j = 0; j < 8; ++j) v[j] = -INFINITY;
  }
  __shared__ float red[8];
  for (int o = 32; o; o >>= 1) m = fmaxf(m, __shfl_xor(m, o, 64));
  if (l == 0) red[w] = m;
  __syncthreads();
  m = fmaxf(fmaxf(red[0], red[1]), fmaxf(red[2], red[3]));

  float s = 0.f;
#pragma unroll
  for (int j = 0; j < 8; ++j) s += __expf(v[j] - m);  // exp(-inf)=0
  for (int o = 32; o; o >>= 1) s += __shfl_xor(s, o, 64);
  if (l == 0) red[4 + w] = s;
  __syncthreads();
  if (tid == 0) {
    s = (red[4] + red[5]) + (red[6] + red[7]);
    stats[(long)row * 2] = m;
    stats[(long)row * 2 + 1] = 1.0f / s;
  }
}

// ---------------- merged casts (one dispatch) ----------------
// blocks [0,12288): X casts (y = bid/4096).  blocks [12288,15360): W^T casts.
__global__ __launch_bounds__(256) void cast_all_kernel(
    const float* __restrict__ x0, const float* __restrict__ x1,
    const float* __restrict__ x2, u16* __restrict__ o0, u16* __restrict__ o1,
    u16* __restrict__ o2, const float* __restrict__ wk,
    const float* __restrict__ wv, const float* __restrict__ wq,
    u16* __restrict__ ok, u16* __restrict__ ov, u16* __restrict__ oq) {
  const int bid = blockIdx.x;
  if (bid < 12288) {
    const int y = bid >> 12;
    const float* in = y == 0 ? x0 : (y == 1 ? x1 : x2);
    u16* out = y == 0 ? o0 : (y == 1 ? o1 : o2);
    long i = ((long)(bid & 4095) * 256 + threadIdx.x) * 8;
    f32x4 a = *(const f32x4*)(in + i);
    f32x4 b = *(const f32x4*)(in + i + 4);
    s16x8 o;
#pragma unroll
    for (int j = 0; j < 4; ++j) {
      o[j] = (short)f2h(a[j]);
      o[4 + j] = (short)f2h(b[j]);
    }
    *(s16x8*)(out + i) = o;
  } else {
    __shared__ float tile[32][33];
    const int t = bid - 12288;
    const int z = t >> 10;
    const int loc = t & 1023;
    const int bx = loc & 31, by = loc >> 5;
    const float* w = z == 0 ? wk : (z == 1 ? wv : wq);
    u16* o = z == 0 ? ok : (z == 1 ? ov : oq);
    const float scale = (z == 2) ? 0.03125f : 1.0f;  // 1/sqrt(1024) into WQ
    const int lx = threadIdx.x & 31, ly = threadIdx.x >> 5;
#pragma unroll
    for (int j = 0; j < 32; j += 8)
      tile[ly + j][lx] = w[(long)(by * 32 + ly + j) * 1024 + bx * 32 + lx];
    __syncthreads();
#pragma unroll
    for (int j = 0; j < 32; j += 8)
      o[(long)(bx * 32 + ly + j) * 1024 + by * 32 + lx] =
          f2h(tile[lx][ly + j] * scale);
  }
}

// ---------------- launch ----------------
extern "C" void kernel_launch(void* const* d_in, const int* in_sizes, int n_in,
                              void* d_out, int out_size, void* d_ws, size_t ws_size,
                              hipStream_t stream) {
  const float* Xk = (const float*)d_in[0];
  const float* Xv = (const float*)d_in[1];
  const float* Xq = (const float*)d_in[2];
  const float* WK = (const float*)d_in[3];
  const float* WV = (const float*)d_in[4];
  const float* WQ = (const float*)d_in[5];

  const int Bn = 4, S = 2048, D = 1024;
  const long NX = (long)Bn * S * D;

  // ws layout (aliasing):
  //  region0 [0,64MB): Xk,Xv,Xq f16 (50.3MB) -> later scores f16 (32MB)
  //  region1: WKt,WVt,WQt f16 (6MB)
  //  region2: K,Q f16 (32MB) -> later row stats (64KB, aliases dead K)
  //  region3: V^T f16 (16MB)
  const size_t r0 = (size_t)Bn * S * S * 4;
  const size_t r1 = r0 + 3ull * D * D * 2;
  const size_t r2 = r1 + 2ull * NX * 2;
  const size_t NEED = r2 + (size_t)NX * 2;
  if (ws_size < NEED) {
    hipMemsetAsync(d_out, 0, (size_t)out_size * 4, stream);
    return;
  }
  char* ws = (char*)d_ws;
  u16* xkb = (u16*)ws;
  u16* xvb = xkb + NX;
  u16* xqb = xvb + NX;
  u16* scoresH = (u16*)ws;          // aliases dead X after projections
  u16* wkt = (u16*)(ws + r0);
  u16* wvt = wkt + D * D;
  u16* wqt = wvt + D * D;
  u16* Kb = (u16*)(ws + r1);
  u16* Qb = Kb + NX;
  float* stats = (float*)(ws + r1); // aliases dead K after qkt (64KB)
  u16* Vt = (u16*)(ws + r2);

  cast_all_kernel<<<dim3(15360), 256, 0, stream>>>(Xk, Xv, Xq, xkb, xvb, xqb,
                                                   WK, WV, WQ, wkt, wvt, wqt);
  proj_kernel<<<dim3(512, 3), 256, 0, stream>>>(xkb, xqb, xvb, wkt, wqt, wvt,
                                                Kb, Qb, Vt);
  qkt_kernel<<<dim3(544), 256, 0, stream>>>(Qb, Kb, scoresH);
  rowstat_kernel<<<dim3(8192), 256, 0, stream>>>(scoresH, stats);
  pv_kernel<<<dim3(512), 256, 0, stream>>>(scoresH, Vt, stats, (float*)d_out);
}

// Round 9
// 156.229 us; speedup vs baseline: 1.1986x; 1.1986x over previous
//
#include <hip/hip_runtime.h>
#include <hip/hip_bf16.h>

typedef unsigned short u16;
typedef _Float16 f16;
typedef __attribute__((ext_vector_type(8))) short s16x8;
typedef __attribute__((ext_vector_type(8))) _Float16 f16x8;
typedef __attribute__((ext_vector_type(4))) float f32x4;
typedef __attribute__((ext_vector_type(4))) unsigned short u16x4;

// ---------------- MFMA wrapper (f16) ----------------
template <typename T>
__device__ __forceinline__ auto mfma_try(T a, T b, f32x4 c, int)
    -> decltype(__builtin_amdgcn_mfma_f32_16x16x32_f16(a, b, c, 0, 0, 0)) {
  return __builtin_amdgcn_mfma_f32_16x16x32_f16(a, b, c, 0, 0, 0);
}
template <typename T>
__device__ __forceinline__ f32x4 mfma_try(T a, T b, f32x4 c, long) {
  return __builtin_amdgcn_mfma_f32_16x16x32_f16(
      __builtin_bit_cast(f16x8, a), __builtin_bit_cast(f16x8, b), c, 0, 0, 0);
}
__device__ __forceinline__ f32x4 MFMA16(s16x8 a, s16x8 b, f32x4 c) {
  return mfma_try(a, b, c, 0);
}

__device__ __forceinline__ void gload16(const void* g, void* s) {
  __builtin_amdgcn_global_load_lds(
      (const __attribute__((address_space(1))) void*)g,
      (__attribute__((address_space(3))) void*)s, 16, 0, 0);
}

__device__ __forceinline__ u16 f2h(float x) {
  f16 h = (f16)x;
  u16 u;
  __builtin_memcpy(&u, &h, 2);
  return u;
}
__device__ __forceinline__ float h2f(u16 u) {
  f16 h;
  __builtin_memcpy(&h, &u, 2);
  return (float)h;
}

#define LDS_SWZ(r, cb) ((cb) ^ (((r)&7) << 4))

// =============== 128x128x64 2-phase dbuf core (proven, ~835 TF) ============
struct Geom {
  int srow[4], scol[4];
  int w, l, wr, wc;
};

__device__ __forceinline__ Geom make_geom() {
  Geom g;
  int tid = threadIdx.x;
  g.w = tid >> 6; g.l = tid & 63;
  g.wr = g.w >> 1; g.wc = g.w & 1;
#pragma unroll
  for (int i = 0; i < 4; ++i) {
    int off = i * 4096 + g.w * 1024 + g.l * 16;
    int r = off >> 7, cb = off & 127;
    g.srow[i] = r;
    g.scol[i] = LDS_SWZ(r, cb) >> 1;  // pre-swizzled global source (rule 21)
  }
  return g;
}

__device__ __forceinline__ void stage(const u16* pan, int ld, int k0,
                                      char* lds, const Geom& g) {
#pragma unroll
  for (int i = 0; i < 4; ++i)
    gload16(pan + (long)g.srow[i] * ld + k0 + g.scol[i],
            lds + i * 4096 + g.w * 1024);
}

__device__ __forceinline__ void compute_step(const char* lA, const char* lB,
                                             const Geom& g, f32x4 acc[4][4]) {
#pragma unroll
  for (int ks = 0; ks < 2; ++ks) {
    s16x8 af[4], bg[4];
#pragma unroll
    for (int m = 0; m < 4; ++m) {
      int r = g.wr * 64 + m * 16 + (g.l & 15);
      int cb = ks * 64 + ((g.l >> 4) << 4);
      af[m] = *(const s16x8*)(lA + r * 128 + LDS_SWZ(r, cb));
    }
#pragma unroll
    for (int n = 0; n < 4; ++n) {
      int r = g.wc * 64 + n * 16 + (g.l & 15);
      int cb = ks * 64 + ((g.l >> 4) << 4);
      bg[n] = *(const s16x8*)(lB + r * 128 + LDS_SWZ(r, cb));
    }
#pragma unroll
    for (int m = 0; m < 4; ++m)
#pragma unroll
      for (int n = 0; n < 4; ++n)
        acc[m][n] = MFMA16(af[m], bg[n], acc[m][n]);
  }
}

// lA/lB each hold 2 buffers of 16 KB at +0 / +16384.
__device__ __forceinline__ void gemm_core(const u16* Apan, int lda,
                                          const u16* Bpan, int ldb, int nsteps,
                                          char* lA, char* lB, const Geom& g,
                                          f32x4 acc[4][4]) {
  stage(Apan, lda, 0, lA, g);
  stage(Bpan, ldb, 0, lB, g);
  __syncthreads();  // drains vmcnt: buf0 ready
  for (int t = 0; t < nsteps; ++t) {
    int cur = (t & 1) << 14;
    if (t + 1 < nsteps) {
      int nxt = ((t + 1) & 1) << 14;
      stage(Apan, lda, (t + 1) * 64, lA + nxt, g);  // prefetch overlaps MFMA
      stage(Bpan, ldb, (t + 1) * 64, lB + nxt, g);
    }
    compute_step(lA + cur, lB + cur, g, acc);
    if (t + 1 < nsteps) __syncthreads();  // one barrier per K-step
  }
}

// ---------------- kernels ----------------
// merged projections: y=0 K, y=1 Q, y=2 V^T. M folded over batch (8192).
__global__ __launch_bounds__(256, 2) void proj_kernel(
    const u16* __restrict__ xk, const u16* __restrict__ xq, const u16* __restrict__ xv,
    const u16* __restrict__ wk, const u16* __restrict__ wq, const u16* __restrict__ wv,
    u16* __restrict__ K, u16* __restrict__ Q, u16* __restrict__ Vt) {
  __shared__ char lds[65536];
  const int y = blockIdx.y;
  const u16* X = y == 0 ? xk : (y == 1 ? xq : xv);
  const u16* W = y == 0 ? wk : (y == 1 ? wq : wv);
  const int bx = blockIdx.x;
  const int swz = (bx & 7) * 64 + (bx >> 3);  // 512 blocks, bijective
  const int tm = swz >> 3, tn = swz & 7;
  Geom g = make_geom();
  f32x4 acc[4][4] = {};
  gemm_core(X + (long)tm * 128 * 1024, 1024, W + (long)tn * 128 * 1024, 1024,
            16, lds, lds + 32768, g, acc);
  const int rg0 = tm * 128 + g.wr * 64, cg0 = tn * 128 + g.wc * 64;
  if (y < 2) {
    u16* C = y == 0 ? K : Q;
#pragma unroll
    for (int m = 0; m < 4; ++m)
#pragma unroll
      for (int n = 0; n < 4; ++n)
#pragma unroll
        for (int j = 0; j < 4; ++j) {
          int rg = rg0 + m * 16 + ((g.l >> 4) << 2) + j;
          int cg = cg0 + n * 16 + (g.l & 15);
          C[(long)rg * 1024 + cg] = f2h(acc[m][n][j]);
        }
  } else {
#pragma unroll
    for (int m = 0; m < 4; ++m) {
      int rg = rg0 + m * 16 + ((g.l >> 4) << 2);
      int b = rg >> 11, rl = rg & 2047;
#pragma unroll
      for (int n = 0; n < 4; ++n) {
        int cg = cg0 + n * 16 + (g.l & 15);
        u16x4 pk;
#pragma unroll
        for (int j = 0; j < 4; ++j) pk[j] = f2h(acc[m][n][j]);
        *(u16x4*)(Vt + (long)b * (1024 * 2048) + (long)cg * 2048 + rl) = pk;
      }
    }
  }
}

// scores = Q K^T, triangular tile grid, f16 out. 544 blocks (4 batches x 136).
__global__ __launch_bounds__(256, 2) void qkt_kernel(
    const u16* __restrict__ Q, const u16* __restrict__ K, u16* __restrict__ S) {
  __shared__ char lds[65536];
  const int bx = blockIdx.x;
  const int swz = (bx & 7) * 68 + (bx >> 3);  // 544 = 8*68, bijective
  const int b = swz / 136;
  int t = swz - b * 136;
  int tm = 0;
  while (t > tm) { t -= tm + 1; ++tm; }
  const int tn = t;
  Geom g = make_geom();
  f32x4 acc[4][4] = {};
  const u16* Qb = Q + (long)b * 2048 * 1024;
  const u16* Kb = K + (long)b * 2048 * 1024;
  gemm_core(Qb + (long)tm * 128 * 1024, 1024, Kb + (long)tn * 128 * 1024, 1024,
            16, lds, lds + 32768, g, acc);
  u16* Sb = S + (long)b * 2048 * 2048;
  const int rg0 = tm * 128 + g.wr * 64, cg0 = tn * 128 + g.wc * 64;
#pragma unroll
  for (int m = 0; m < 4; ++m)
#pragma unroll
    for (int n = 0; n < 4; ++n)
#pragma unroll
      for (int j = 0; j < 4; ++j) {
        int rg = rg0 + m * 16 + ((g.l >> 4) << 2) + j;
        int cg = cg0 + n * 16 + (g.l & 15);
        Sb[(long)rg * 2048 + cg] = f2h(acc[m][n][j]);
      }
}

// O = P V (k-limited), f32 out. 512 blocks.
__global__ __launch_bounds__(256, 2) void pv_kernel(
    const u16* __restrict__ P, const u16* __restrict__ Vt, float* __restrict__ O) {
  __shared__ char lds[65536];
  const int bx = blockIdx.x;
  const int swz = (bx & 7) * 64 + (bx >> 3);
  const int b = swz >> 7, loc = swz & 127;
  const int tm = loc >> 3, tn = loc & 7;
  Geom g = make_geom();
  f32x4 acc[4][4] = {};
  gemm_core(P + ((long)b * 2048 + tm * 128) * 2048, 2048,
            Vt + (long)b * 1024 * 2048 + (long)tn * 128 * 2048, 2048,
            (tm + 1) * 2, lds, lds + 32768, g, acc);
  const int rg0 = tm * 128 + g.wr * 64, cg0 = tn * 128 + g.wc * 64;
#pragma unroll
  for (int m = 0; m < 4; ++m)
#pragma unroll
    for (int n = 0; n < 4; ++n)
#pragma unroll
      for (int j = 0; j < 4; ++j) {
        int rg = rg0 + m * 16 + ((g.l >> 4) << 2) + j;
        int cg = cg0 + n * 16 + (g.l & 15);
        O[((long)b * 2048 + rg) * 1024 + cg] = acc[m][n][j];
      }
}

// ---------------- causal softmax: f16 scores -> f16 P ----------------
// ROW-PAIRED: block handles rows i and 2047-i (uniform 2049 valid elems).
// Read-skip fully-masked chunks; write-skip beyond klim (pv's k-limit means
// P[k >= (i/128+1)*128] is never read).
__global__ __launch_bounds__(256) void softmax_causal(
    const u16* __restrict__ S, u16* __restrict__ P) {
  const int bid = blockIdx.x;  // 4096 = 4 batches * 1024 pairs
  const int b = bid >> 10, i0 = bid & 1023;
  const int tid = threadIdx.x;
  const int l = tid & 63, w = tid >> 6;
  const int base = tid * 8;
  __shared__ float red[8];

#pragma unroll
  for (int ph = 0; ph < 2; ++ph) {
    const int i_q = ph ? (2047 - i0) : i0;
    const long row = (long)b * 2048 + i_q;
    const int klim = ((i_q >> 7) + 1) << 7;
    const u16* sr = S + row * 2048;
    u16* pr = P + row * 2048;

    float v[8];
    float m = -INFINITY;
    if (base <= i_q) {  // chunk has at least one valid element
      s16x8 raw = *(const s16x8*)(sr + base);
#pragma unroll
      for (int j = 0; j < 8; ++j) {
        float x = h2f((u16)raw[j]);
        x = (base + j <= i_q) ? x : -INFINITY;  // mask BEFORE any use
        v[j] = x;
        m = fmaxf(m, x);
      }
    } else {
#pragma unroll
      for (int j = 0; j < 8; ++j) v[j] = -INFINITY;
    }
    for (int o = 32; o; o >>= 1) m = fmaxf(m, __shfl_xor(m, o, 64));
    if (l == 0) red[w] = m;
    __syncthreads();
    m = fmaxf(fmaxf(red[0], red[1]), fmaxf(red[2], red[3]));

    float s = 0.f;
#pragma unroll
    for (int j = 0; j < 8; ++j) {
      v[j] = __expf(v[j] - m);  // exp(-inf)=0 for masked
      s += v[j];
    }
    for (int o = 32; o; o >>= 1) s += __shfl_xor(s, o, 64);
    if (l == 0) red[4 + w] = s;
    __syncthreads();
    s = (red[4] + red[5]) + (red[6] + red[7]);
    float inv = 1.0f / s;

    if (base < klim) {
      s16x8 o;
#pragma unroll
      for (int j = 0; j < 8; ++j) o[j] = (short)f2h(v[j] * inv);
      *(s16x8*)(pr + base) = o;
    }
    __syncthreads();  // red[] reuse fence between phases
  }
}

// ---------------- merged casts (one dispatch) ----------------
// blocks [0,12288): X casts (y = bid/4096).  blocks [12288,15360): W^T casts.
__global__ __launch_bounds__(256) void cast_all_kernel(
    const float* __restrict__ x0, const float* __restrict__ x1,
    const float* __restrict__ x2, u16* __restrict__ o0, u16* __restrict__ o1,
    u16* __restrict__ o2, const float* __restrict__ wk,
    const float* __restrict__ wv, const float* __restrict__ wq,
    u16* __restrict__ ok, u16* __restrict__ ov, u16* __restrict__ oq) {
  const int bid = blockIdx.x;
  if (bid < 12288) {
    const int y = bid >> 12;  // /4096
    const float* in = y == 0 ? x0 : (y == 1 ? x1 : x2);
    u16* out = y == 0 ? o0 : (y == 1 ? o1 : o2);
    long i = ((long)(bid & 4095) * 256 + threadIdx.x) * 8;
    f32x4 a = *(const f32x4*)(in + i);
    f32x4 b = *(const f32x4*)(in + i + 4);
    s16x8 o;
#pragma unroll
    for (int j = 0; j < 4; ++j) {
      o[j] = (short)f2h(a[j]);
      o[4 + j] = (short)f2h(b[j]);
    }
    *(s16x8*)(out + i) = o;
  } else {
    __shared__ float tile[32][33];
    const int t = bid - 12288;
    const int z = t >> 10;             // /1024
    const int loc = t & 1023;
    const int bx = loc & 31, by = loc >> 5;
    const float* w = z == 0 ? wk : (z == 1 ? wv : wq);
    u16* o = z == 0 ? ok : (z == 1 ? ov : oq);
    const float scale = (z == 2) ? 0.03125f : 1.0f;  // 1/sqrt(1024) into WQ
    const int lx = threadIdx.x & 31, ly = threadIdx.x >> 5;
#pragma unroll
    for (int j = 0; j < 32; j += 8)
      tile[ly + j][lx] = w[(long)(by * 32 + ly + j) * 1024 + bx * 32 + lx];
    __syncthreads();
#pragma unroll
    for (int j = 0; j < 32; j += 8)
      o[(long)(bx * 32 + ly + j) * 1024 + by * 32 + lx] =
          f2h(tile[lx][ly + j] * scale);
  }
}

// ---------------- launch ----------------
extern "C" void kernel_launch(void* const* d_in, const int* in_sizes, int n_in,
                              void* d_out, int out_size, void* d_ws, size_t ws_size,
                              hipStream_t stream) {
  const float* Xk = (const float*)d_in[0];
  const float* Xv = (const float*)d_in[1];
  const float* Xq = (const float*)d_in[2];
  const float* WK = (const float*)d_in[3];
  const float* WV = (const float*)d_in[4];
  const float* WQ = (const float*)d_in[5];

  const int Bn = 4, S = 2048, D = 1024;
  const long NX = (long)Bn * S * D;

  // ws layout (aliasing):
  //  region0 [0,64MB): Xk,Xv,Xq f16 (50.3MB) -> later scores f16 (32MB)
  //  region1: WKt,WVt,WQt f16 (6MB)
  //  region2: K,Q f16 (32MB) -> later P f16 (32MB)
  //  region3: V^T f16 (16MB)
  const size_t r0 = (size_t)Bn * S * S * 4;
  const size_t r1 = r0 + 3ull * D * D * 2;
  const size_t r2 = r1 + 2ull * NX * 2;
  const size_t NEED = r2 + (size_t)NX * 2;
  if (ws_size < NEED) {
    hipMemsetAsync(d_out, 0, (size_t)out_size * 4, stream);
    return;
  }
  char* ws = (char*)d_ws;
  u16* xkb = (u16*)ws;
  u16* xvb = xkb + NX;
  u16* xqb = xvb + NX;
  u16* scoresH = (u16*)ws;  // aliases dead X after projections
  u16* wkt = (u16*)(ws + r0);
  u16* wvt = wkt + D * D;
  u16* wqt = wvt + D * D;
  u16* Kb = (u16*)(ws + r1);
  u16* Qb = Kb + NX;
  u16* Pb = (u16*)(ws + r1);  // aliases dead K,Q after qkt
  u16* Vt = (u16*)(ws + r2);

  cast_all_kernel<<<dim3(15360), 256, 0, stream>>>(Xk, Xv, Xq, xkb, xvb, xqb,
                                                   WK, WV, WQ, wkt, wvt, wqt);
  proj_kernel<<<dim3(512, 3), 256, 0, stream>>>(xkb, xqb, xvb, wkt, wqt, wvt,
                                                Kb, Qb, Vt);
  qkt_kernel<<<dim3(544), 256, 0, stream>>>(Qb, Kb, scoresH);
  softmax_causal<<<dim3(4096), 256, 0, stream>>>(scoresH, Pb);
  pv_kernel<<<dim3(512), 256, 0, stream>>>(Pb, Vt, (float*)d_out);
}